// Round 2
// baseline (1231.426 us; speedup 1.0000x reference)
//
#include <hip/hip_runtime.h>

#define T_TOK 4096
#define H_DIM 1024
#define I_DIM 4096
#define NE 8
#define INTER_ROWS 9216

typedef _Float16 f16;
typedef _Float16 f16x8 __attribute__((ext_vector_type(8)));
typedef _Float16 f16x4 __attribute__((ext_vector_type(4)));
typedef float f32x4 __attribute__((ext_vector_type(4)));

#define GLOBAL_AS __attribute__((address_space(1)))
#define LDS_AS __attribute__((address_space(3)))

__device__ __forceinline__ void gload_lds16(const void* g, void* l) {
  __builtin_amdgcn_global_load_lds((GLOBAL_AS const unsigned int*)g,
                                   (LDS_AS unsigned int*)l, 16, 0, 0);
}

// ---------------------------------------------------------------- cast x -> fp16
__global__ void cast_x_kernel(const float* __restrict__ x, f16* __restrict__ xh) {
  int i = blockIdx.x * 256 + threadIdx.x;
  float4 v = reinterpret_cast<const float4*>(x)[i];
  f16x4 o = {(f16)v.x, (f16)v.y, (f16)v.z, (f16)v.w};
  reinterpret_cast<f16x4*>(xh)[i] = o;
}

// ---------------------------------------------------------------- router (1 wave / token)
__global__ void router_kernel(const float* __restrict__ x, const float* __restrict__ gw,
                              int* __restrict__ counts, int* __restrict__ lists,
                              float* __restrict__ wgts) {
  const int t = blockIdx.x;
  const int l = threadIdx.x;
  const float* xr = x + (size_t)t * H_DIM;
  float acc[NE];
#pragma unroll
  for (int e = 0; e < NE; ++e) acc[e] = 0.f;
  for (int k = l; k < H_DIM; k += 64) {
    float xv = xr[k];
#pragma unroll
    for (int e = 0; e < NE; ++e) acc[e] += xv * gw[k * NE + e];
  }
#pragma unroll
  for (int e = 0; e < NE; ++e) {
    float v = acc[e];
#pragma unroll
    for (int off = 32; off > 0; off >>= 1) v += __shfl_xor(v, off);
    acc[e] = v;
  }
  if (l == 0) {
    int i1 = 0;
#pragma unroll
    for (int e = 1; e < NE; ++e)
      if (acc[e] > acc[i1]) i1 = e;   // strict > : lowest index wins ties (matches top_k)
    int i2 = (i1 == 0) ? 1 : 0;
#pragma unroll
    for (int e = 0; e < NE; ++e)
      if (e != i1 && acc[e] > acc[i2]) i2 = e;
    // renormalized top-2 softmax: denominators cancel
    float wA = 1.f / (1.f + __expf(acc[i2] - acc[i1]));
    float wB = 1.f - wA;
    int p1 = atomicAdd(&counts[i1], 1);
    lists[i1 * T_TOK + p1] = t;
    wgts[i1 * T_TOK + p1] = wA;
    int p2 = atomicAdd(&counts[i2], 1);
    lists[i2 * T_TOK + p2] = t;
    wgts[i2 * T_TOK + p2] = wB;
  }
}

// ---------------------------------------------------------------- padded prefix offsets
__global__ void prefix_kernel(const int* __restrict__ counts, int* __restrict__ bases) {
  if (threadIdx.x == 0) {
    int s = 0;
#pragma unroll
    for (int e = 0; e < NE; ++e) {
      bases[e] = s;
      s += (counts[e] + 127) & ~127;
    }
  }
}

// ---------------------------------------------------------------- GEMM A: inter = silu(x@w1)*(x@w3)
__global__ __launch_bounds__(256, 2) void gemm_a_kernel(
    const f16* __restrict__ xh, const float* __restrict__ w1s, const float* __restrict__ w3s,
    const int* __restrict__ counts, const int* __restrict__ bases,
    const int* __restrict__ lists, f16* __restrict__ inter) {
  const int z = blockIdx.z;
  const int cnt = counts[z];
  const int r0 = blockIdx.y * 128;
  if (r0 >= cnt) return;
  const int base = bases[z];
  const int c0 = blockIdx.x * 128;
  const int tid = threadIdx.x;
  const int lane = tid & 63;
  const int wid = tid >> 6;
  const int wm = wid >> 1, wn = wid & 1;
  const int lrow = lane & 15, lk = lane >> 4;

  __shared__ __align__(16) f16 As[128 * 64];
  __shared__ __align__(16) f16 B1s[128 * 64];
  __shared__ __align__(16) f16 B3s[128 * 64];

  const int* lst = lists + z * T_TOK;
  const float* w1 = w1s + (size_t)z * H_DIM * I_DIM;
  const float* w3 = w3s + (size_t)z * H_DIM * I_DIM;

  // A staging sources (gathered rows, inverse-swizzled source slot; LDS dest linear)
  const f16* asrc[4];
#pragma unroll
  for (int i = 0; i < 4; ++i) {
    int sf = i * 256 + tid;
    int row = sf >> 3;
    int s = sf & 7;
    int tok = lst[r0 + row];  // zeroed past cnt -> token 0 (safe pad)
    asrc[i] = xh + (size_t)tok * H_DIM + (s ^ (row & 7)) * 8;
  }
  const int bn = tid & 127;
  const int kb0 = tid >> 7;
  const float* b1p = w1 + c0 + bn;
  const float* b3p = w3 + c0 + bn;

  const f32x4 z4 = {0.f, 0.f, 0.f, 0.f};
  f32x4 acc1[4][4], acc3[4][4];
#pragma unroll
  for (int m = 0; m < 4; ++m)
#pragma unroll
    for (int n = 0; n < 4; ++n) { acc1[m][n] = z4; acc3[m][n] = z4; }

  for (int k0 = 0; k0 < H_DIM; k0 += 64) {
#pragma unroll
    for (int i = 0; i < 4; ++i)
      gload_lds16(asrc[i] + k0, &As[(i * 256 + wid * 64) * 8]);
    // B: column-gather 8 k-values per lane, cvt, transposed [n][k] swizzled store
#pragma unroll
    for (int rr = 0; rr < 4; ++rr) {
      int kb = kb0 + 2 * rr;
      const float* p1 = b1p + (size_t)(k0 + kb * 8) * I_DIM;
      const float* p3 = b3p + (size_t)(k0 + kb * 8) * I_DIM;
      float v1[8], v3[8];
#pragma unroll
      for (int j = 0; j < 8; ++j) v1[j] = p1[(size_t)j * I_DIM];
#pragma unroll
      for (int j = 0; j < 8; ++j) v3[j] = p3[(size_t)j * I_DIM];
      f16x8 h1, h3;
#pragma unroll
      for (int j = 0; j < 8; ++j) { h1[j] = (f16)v1[j]; h3[j] = (f16)v3[j]; }
      int ls = bn * 64 + ((kb ^ (bn & 7)) * 8);
      *reinterpret_cast<f16x8*>(&B1s[ls]) = h1;
      *reinterpret_cast<f16x8*>(&B3s[ls]) = h3;
    }
    __syncthreads();
#pragma unroll
    for (int kk = 0; kk < 2; ++kk) {
      const int cs = kk * 4 + lk;
      f16x8 af[4], b1f[4], b3f[4];
#pragma unroll
      for (int m = 0; m < 4; ++m) {
        int row = wm * 64 + m * 16 + lrow;
        af[m] = *reinterpret_cast<const f16x8*>(&As[row * 64 + ((cs ^ (row & 7)) * 8)]);
      }
#pragma unroll
      for (int n = 0; n < 4; ++n) {
        int row = wn * 64 + n * 16 + lrow;
        int off = row * 64 + ((cs ^ (row & 7)) * 8);
        b1f[n] = *reinterpret_cast<const f16x8*>(&B1s[off]);
        b3f[n] = *reinterpret_cast<const f16x8*>(&B3s[off]);
      }
#pragma unroll
      for (int m = 0; m < 4; ++m)
#pragma unroll
        for (int n = 0; n < 4; ++n) {
          acc1[m][n] = __builtin_amdgcn_mfma_f32_16x16x32_f16(af[m], b1f[n], acc1[m][n], 0, 0, 0);
          acc3[m][n] = __builtin_amdgcn_mfma_f32_16x16x32_f16(af[m], b3f[n], acc3[m][n], 0, 0, 0);
        }
    }
    __syncthreads();
  }
  // epilogue: SwiGLU, fp16 store (pad rows beyond cnt hold token-0 garbage; never combined)
#pragma unroll
  for (int m = 0; m < 4; ++m)
#pragma unroll
    for (int n = 0; n < 4; ++n)
#pragma unroll
      for (int r = 0; r < 4; ++r) {
        int grow = base + r0 + wm * 64 + m * 16 + lk * 4 + r;
        int gcol = c0 + wn * 64 + n * 16 + lrow;
        float s1 = acc1[m][n][r];
        float s3 = acc3[m][n][r];
        float sv = s1 / (1.f + __expf(-s1));
        inter[(size_t)grow * I_DIM + gcol] = (f16)(sv * s3);
      }
}

// ---------------------------------------------------------------- GEMM B: out[tok] += wgt * inter@w2
__global__ __launch_bounds__(256, 2) void gemm_b_kernel(
    const f16* __restrict__ inter, const float* __restrict__ w2s,
    const int* __restrict__ counts, const int* __restrict__ bases,
    const int* __restrict__ lists, const float* __restrict__ wgts,
    float* __restrict__ out) {
  const int z = blockIdx.z;
  const int cnt = counts[z];
  const int r0 = blockIdx.y * 128;
  if (r0 >= cnt) return;
  const int base = bases[z];
  const int c0 = blockIdx.x * 128;
  const int tid = threadIdx.x;
  const int lane = tid & 63;
  const int wid = tid >> 6;
  const int wm = wid >> 1, wn = wid & 1;
  const int lrow = lane & 15, lk = lane >> 4;

  __shared__ __align__(16) f16 As[128 * 64];
  __shared__ __align__(16) f16 Bs[128 * 64];

  const int* lst = lists + z * T_TOK;
  const float* wgt = wgts + z * T_TOK;
  const float* w2 = w2s + (size_t)z * I_DIM * H_DIM;

  const f16* asrc[4];
#pragma unroll
  for (int i = 0; i < 4; ++i) {
    int sf = i * 256 + tid;
    int row = sf >> 3;
    int s = sf & 7;
    asrc[i] = inter + (size_t)(base + r0 + row) * I_DIM + (s ^ (row & 7)) * 8;
  }
  const int bn = tid & 127;
  const int kb0 = tid >> 7;
  const float* bp = w2 + c0 + bn;

  const f32x4 z4 = {0.f, 0.f, 0.f, 0.f};
  f32x4 acc[4][4];
#pragma unroll
  for (int m = 0; m < 4; ++m)
#pragma unroll
    for (int n = 0; n < 4; ++n) acc[m][n] = z4;

  for (int k0 = 0; k0 < I_DIM; k0 += 64) {
#pragma unroll
    for (int i = 0; i < 4; ++i)
      gload_lds16(asrc[i] + k0, &As[(i * 256 + wid * 64) * 8]);
#pragma unroll
    for (int rr = 0; rr < 4; ++rr) {
      int kb = kb0 + 2 * rr;
      const float* p = bp + (size_t)(k0 + kb * 8) * H_DIM;
      float v[8];
#pragma unroll
      for (int j = 0; j < 8; ++j) v[j] = p[(size_t)j * H_DIM];
      f16x8 h;
#pragma unroll
      for (int j = 0; j < 8; ++j) h[j] = (f16)v[j];
      int ls = bn * 64 + ((kb ^ (bn & 7)) * 8);
      *reinterpret_cast<f16x8*>(&Bs[ls]) = h;
    }
    __syncthreads();
#pragma unroll
    for (int kk = 0; kk < 2; ++kk) {
      const int cs = kk * 4 + lk;
      f16x8 af[4], bf[4];
#pragma unroll
      for (int m = 0; m < 4; ++m) {
        int row = wm * 64 + m * 16 + lrow;
        af[m] = *reinterpret_cast<const f16x8*>(&As[row * 64 + ((cs ^ (row & 7)) * 8)]);
      }
#pragma unroll
      for (int n = 0; n < 4; ++n) {
        int row = wn * 64 + n * 16 + lrow;
        bf[n] = *reinterpret_cast<const f16x8*>(&Bs[row * 64 + ((cs ^ (row & 7)) * 8)]);
      }
#pragma unroll
      for (int m = 0; m < 4; ++m)
#pragma unroll
        for (int n = 0; n < 4; ++n)
          acc[m][n] = __builtin_amdgcn_mfma_f32_16x16x32_f16(af[m], bf[n], acc[m][n], 0, 0, 0);
    }
    __syncthreads();
  }
  // epilogue: gather token/weight, ATOMIC accumulate — tokens are unique within one
  // expert's list, but the SAME token appears in two different experts' lists and
  // those blocks run concurrently (blockIdx.z spans experts). Non-atomic += raced
  // and dropped contributions (round-1 absmax 0.80). Two commutative fp32 addends
  // onto a zeroed buffer -> order-independent, deterministic.
#pragma unroll
  for (int m = 0; m < 4; ++m)
#pragma unroll
    for (int r = 0; r < 4; ++r) {
      int ri = r0 + wm * 64 + m * 16 + lk * 4 + r;
      if (ri < cnt) {
        int tok = lst[ri];
        float wg = wgt[ri];
        float* orow = out + (size_t)tok * H_DIM + c0 + wn * 64 + lrow;
#pragma unroll
        for (int n = 0; n < 4; ++n) atomicAdd(&orow[n * 16], wg * acc[m][n][r]);
      }
    }
}

// ---------------------------------------------------------------- host
extern "C" void kernel_launch(void* const* d_in, const int* in_sizes, int n_in,
                              void* d_out, int out_size, void* d_ws, size_t ws_size,
                              hipStream_t stream) {
  const float* x = (const float*)d_in[0];
  const float* gw = (const float*)d_in[1];
  const float* w1s = (const float*)d_in[2];
  const float* w2s = (const float*)d_in[3];
  const float* w3s = (const float*)d_in[4];
  float* out = (float*)d_out;

  char* ws = (char*)d_ws;
  f16* xh = (f16*)ws;                                  // 8 MiB
  f16* inter = (f16*)(ws + ((size_t)8 << 20));         // 72 MiB (9216 rows x 4096 f16)
  char* meta = ws + ((size_t)80 << 20);
  int* counts = (int*)meta;                            // 32 B
  int* bases = (int*)(meta + 512);                     // 32 B
  int* lists = (int*)(meta + 1024);                    // 128 KiB
  float* wgts = (float*)(meta + 1024 + (size_t)NE * T_TOK * 4);  // 128 KiB

  hipMemsetAsync(out, 0, (size_t)out_size * sizeof(float), stream);
  hipMemsetAsync(meta, 0, 1024 + (size_t)NE * T_TOK * 8, stream);

  cast_x_kernel<<<dim3((T_TOK * H_DIM) / (4 * 256)), dim3(256), 0, stream>>>(x, xh);
  router_kernel<<<dim3(T_TOK), dim3(64), 0, stream>>>(x, gw, counts, lists, wgts);
  prefix_kernel<<<dim3(1), dim3(64), 0, stream>>>(counts, bases);
  gemm_a_kernel<<<dim3(I_DIM / 128, T_TOK / 128, NE), dim3(256), 0, stream>>>(
      xh, w1s, w3s, counts, bases, lists, inter);
  gemm_b_kernel<<<dim3(H_DIM / 128, T_TOK / 128, NE), dim3(256), 0, stream>>>(
      inter, w2s, counts, bases, lists, wgts, out);
}

// Round 3
// 536.598 us; speedup vs baseline: 2.2949x; 2.2949x over previous
//
#include <hip/hip_runtime.h>

#define T_TOK 4096
#define H_DIM 1024
#define I_DIM 4096
#define NE 8
#define INTER_ROWS 9216

typedef _Float16 f16;
typedef _Float16 f16x8 __attribute__((ext_vector_type(8)));
typedef _Float16 f16x4 __attribute__((ext_vector_type(4)));
typedef float f32x4 __attribute__((ext_vector_type(4)));

#define GLOBAL_AS __attribute__((address_space(1)))
#define LDS_AS __attribute__((address_space(3)))

__device__ __forceinline__ void gload_lds16(const void* g, void* l) {
  __builtin_amdgcn_global_load_lds((GLOBAL_AS const unsigned int*)g,
                                   (LDS_AS unsigned int*)l, 16, 0, 0);
}

// ---------------------------------------------------------------- cast x -> fp16
__global__ void cast_x_kernel(const float* __restrict__ x, f16* __restrict__ xh) {
  int i = blockIdx.x * 256 + threadIdx.x;
  float4 v = reinterpret_cast<const float4*>(x)[i];
  f16x4 o = {(f16)v.x, (f16)v.y, (f16)v.z, (f16)v.w};
  reinterpret_cast<f16x4*>(xh)[i] = o;
}

// ---------------------------------------------------------------- transpose+cast weights
// in: fp32 [R][C] row-major (per expert, blockIdx.z). out: fp16 [C][R].
// 64x64 LDS tile, both global sides fully coalesced.
__global__ __launch_bounds__(256) void transpose_cast_kernel(
    const float* __restrict__ w, f16* __restrict__ wt, int R, int C) {
  __shared__ float tile[64][65];
  const int z = blockIdx.z;
  const float* in = w + (size_t)z * R * C;
  f16* out = wt + (size_t)z * R * C;
  const int c0 = blockIdx.x * 64, r0 = blockIdx.y * 64;
  const int tr = threadIdx.x >> 4;        // 0..15
  const int tc = (threadIdx.x & 15) * 4;  // 0,4,..,60
#pragma unroll
  for (int i = 0; i < 4; ++i) {
    int r = tr + i * 16;
    float4 v = *reinterpret_cast<const float4*>(&in[(size_t)(r0 + r) * C + c0 + tc]);
    tile[r][tc] = v.x; tile[r][tc + 1] = v.y; tile[r][tc + 2] = v.z; tile[r][tc + 3] = v.w;
  }
  __syncthreads();
#pragma unroll
  for (int i = 0; i < 4; ++i) {
    int oc = tr + i * 16;  // input col == output row
    f16x4 h;
#pragma unroll
    for (int j = 0; j < 4; ++j) h[j] = (f16)tile[tc + j][oc];
    *reinterpret_cast<f16x4*>(&out[(size_t)(c0 + oc) * R + r0 + tc]) = h;
  }
}

// ---------------------------------------------------------------- router (1 wave / token)
__global__ void router_kernel(const float* __restrict__ x, const float* __restrict__ gw,
                              int* __restrict__ counts, int* __restrict__ lists,
                              float* __restrict__ wgts) {
  const int t = blockIdx.x;
  const int l = threadIdx.x;
  const float* xr = x + (size_t)t * H_DIM;
  float acc[NE];
#pragma unroll
  for (int e = 0; e < NE; ++e) acc[e] = 0.f;
  for (int k = l; k < H_DIM; k += 64) {
    float xv = xr[k];
#pragma unroll
    for (int e = 0; e < NE; ++e) acc[e] += xv * gw[k * NE + e];
  }
#pragma unroll
  for (int e = 0; e < NE; ++e) {
    float v = acc[e];
#pragma unroll
    for (int off = 32; off > 0; off >>= 1) v += __shfl_xor(v, off);
    acc[e] = v;
  }
  if (l == 0) {
    int i1 = 0;
#pragma unroll
    for (int e = 1; e < NE; ++e)
      if (acc[e] > acc[i1]) i1 = e;   // strict > : lowest index wins ties (matches top_k)
    int i2 = (i1 == 0) ? 1 : 0;
#pragma unroll
    for (int e = 0; e < NE; ++e)
      if (e != i1 && acc[e] > acc[i2]) i2 = e;
    // renormalized top-2 softmax: denominators cancel
    float wA = 1.f / (1.f + __expf(acc[i2] - acc[i1]));
    float wB = 1.f - wA;
    int p1 = atomicAdd(&counts[i1], 1);
    lists[i1 * T_TOK + p1] = t;
    wgts[i1 * T_TOK + p1] = wA;
    int p2 = atomicAdd(&counts[i2], 1);
    lists[i2 * T_TOK + p2] = t;
    wgts[i2 * T_TOK + p2] = wB;
  }
}

// ---------------------------------------------------------------- padded prefix offsets
__global__ void prefix_kernel(const int* __restrict__ counts, int* __restrict__ bases) {
  if (threadIdx.x == 0) {
    int s = 0;
#pragma unroll
    for (int e = 0; e < NE; ++e) {
      bases[e] = s;
      s += (counts[e] + 127) & ~127;
    }
  }
}

// ---------------------------------------------------------------- GEMM A: inter = silu(x@w1)*(x@w3)
// w1t/w3t are pre-transposed fp16 [I][H] per expert -> B staging is coalesced gload_lds.
__global__ __launch_bounds__(256, 2) void gemm_a_kernel(
    const f16* __restrict__ xh, const f16* __restrict__ w1t, const f16* __restrict__ w3t,
    const int* __restrict__ counts, const int* __restrict__ bases,
    const int* __restrict__ lists, f16* __restrict__ inter) {
  const int z = blockIdx.z;
  const int cnt = counts[z];
  const int r0 = blockIdx.y * 128;
  if (r0 >= cnt) return;
  const int base = bases[z];
  const int c0 = blockIdx.x * 128;
  const int tid = threadIdx.x;
  const int lane = tid & 63;
  const int wid = tid >> 6;
  const int wm = wid >> 1, wn = wid & 1;
  const int lrow = lane & 15, lk = lane >> 4;

  __shared__ __align__(16) f16 As[128 * 64];
  __shared__ __align__(16) f16 B1s[128 * 64];
  __shared__ __align__(16) f16 B3s[128 * 64];

  const int* lst = lists + z * T_TOK;
  const f16* w1 = w1t + (size_t)z * H_DIM * I_DIM;
  const f16* w3 = w3t + (size_t)z * H_DIM * I_DIM;

  // staging sources (inverse-swizzled source slot; LDS dest linear — rule 21)
  const f16* asrc[4];
  const f16* b1src[4];
  const f16* b3src[4];
#pragma unroll
  for (int i = 0; i < 4; ++i) {
    int sf = i * 256 + tid;
    int row = sf >> 3;
    int s = sf & 7;
    int cofs = (s ^ (row & 7)) * 8;
    int tok = lst[r0 + row];  // zeroed past cnt -> token 0 (safe pad)
    asrc[i] = xh + (size_t)tok * H_DIM + cofs;
    b1src[i] = w1 + (size_t)(c0 + row) * H_DIM + cofs;
    b3src[i] = w3 + (size_t)(c0 + row) * H_DIM + cofs;
  }

  const f32x4 z4 = {0.f, 0.f, 0.f, 0.f};
  f32x4 acc1[4][4], acc3[4][4];
#pragma unroll
  for (int m = 0; m < 4; ++m)
#pragma unroll
    for (int n = 0; n < 4; ++n) { acc1[m][n] = z4; acc3[m][n] = z4; }

  for (int k0 = 0; k0 < H_DIM; k0 += 64) {
#pragma unroll
    for (int i = 0; i < 4; ++i) {
      int ldst = (i * 256 + wid * 64) * 8;
      gload_lds16(asrc[i] + k0, &As[ldst]);
      gload_lds16(b1src[i] + k0, &B1s[ldst]);
      gload_lds16(b3src[i] + k0, &B3s[ldst]);
    }
    __syncthreads();
#pragma unroll
    for (int kk = 0; kk < 2; ++kk) {
      const int cs = kk * 4 + lk;
      f16x8 af[4], b1f[4], b3f[4];
#pragma unroll
      for (int m = 0; m < 4; ++m) {
        int row = wm * 64 + m * 16 + lrow;
        af[m] = *reinterpret_cast<const f16x8*>(&As[row * 64 + ((cs ^ (row & 7)) * 8)]);
      }
#pragma unroll
      for (int n = 0; n < 4; ++n) {
        int row = wn * 64 + n * 16 + lrow;
        int off = row * 64 + ((cs ^ (row & 7)) * 8);
        b1f[n] = *reinterpret_cast<const f16x8*>(&B1s[off]);
        b3f[n] = *reinterpret_cast<const f16x8*>(&B3s[off]);
      }
#pragma unroll
      for (int m = 0; m < 4; ++m)
#pragma unroll
        for (int n = 0; n < 4; ++n) {
          acc1[m][n] = __builtin_amdgcn_mfma_f32_16x16x32_f16(af[m], b1f[n], acc1[m][n], 0, 0, 0);
          acc3[m][n] = __builtin_amdgcn_mfma_f32_16x16x32_f16(af[m], b3f[n], acc3[m][n], 0, 0, 0);
        }
    }
    __syncthreads();
  }
  // epilogue: SwiGLU, fp16 store (pad rows beyond cnt hold token-0 garbage; never combined)
#pragma unroll
  for (int m = 0; m < 4; ++m)
#pragma unroll
    for (int n = 0; n < 4; ++n)
#pragma unroll
      for (int r = 0; r < 4; ++r) {
        int grow = base + r0 + wm * 64 + m * 16 + lk * 4 + r;
        int gcol = c0 + wn * 64 + n * 16 + lrow;
        float s1 = acc1[m][n][r];
        float s3 = acc3[m][n][r];
        float sv = s1 / (1.f + __expf(-s1));
        inter[(size_t)grow * I_DIM + gcol] = (f16)(sv * s3);
      }
}

// ---------------------------------------------------------------- GEMM B: out[tok] += wgt * inter@w2
// w2t is pre-transposed fp16 [H][I] per expert.
__global__ __launch_bounds__(256, 2) void gemm_b_kernel(
    const f16* __restrict__ inter, const f16* __restrict__ w2t,
    const int* __restrict__ counts, const int* __restrict__ bases,
    const int* __restrict__ lists, const float* __restrict__ wgts,
    float* __restrict__ out) {
  const int z = blockIdx.z;
  const int cnt = counts[z];
  const int r0 = blockIdx.y * 128;
  if (r0 >= cnt) return;
  const int base = bases[z];
  const int c0 = blockIdx.x * 128;
  const int tid = threadIdx.x;
  const int lane = tid & 63;
  const int wid = tid >> 6;
  const int wm = wid >> 1, wn = wid & 1;
  const int lrow = lane & 15, lk = lane >> 4;

  __shared__ __align__(16) f16 As[128 * 64];
  __shared__ __align__(16) f16 Bs[128 * 64];

  const int* lst = lists + z * T_TOK;
  const float* wgt = wgts + z * T_TOK;
  const f16* w2 = w2t + (size_t)z * I_DIM * H_DIM;

  const f16* asrc[4];
  const f16* bsrc[4];
#pragma unroll
  for (int i = 0; i < 4; ++i) {
    int sf = i * 256 + tid;
    int row = sf >> 3;
    int s = sf & 7;
    int cofs = (s ^ (row & 7)) * 8;
    asrc[i] = inter + (size_t)(base + r0 + row) * I_DIM + cofs;
    bsrc[i] = w2 + (size_t)(c0 + row) * I_DIM + cofs;
  }

  const f32x4 z4 = {0.f, 0.f, 0.f, 0.f};
  f32x4 acc[4][4];
#pragma unroll
  for (int m = 0; m < 4; ++m)
#pragma unroll
    for (int n = 0; n < 4; ++n) acc[m][n] = z4;

  for (int k0 = 0; k0 < I_DIM; k0 += 64) {
#pragma unroll
    for (int i = 0; i < 4; ++i) {
      int ldst = (i * 256 + wid * 64) * 8;
      gload_lds16(asrc[i] + k0, &As[ldst]);
      gload_lds16(bsrc[i] + k0, &Bs[ldst]);
    }
    __syncthreads();
#pragma unroll
    for (int kk = 0; kk < 2; ++kk) {
      const int cs = kk * 4 + lk;
      f16x8 af[4], bf[4];
#pragma unroll
      for (int m = 0; m < 4; ++m) {
        int row = wm * 64 + m * 16 + lrow;
        af[m] = *reinterpret_cast<const f16x8*>(&As[row * 64 + ((cs ^ (row & 7)) * 8)]);
      }
#pragma unroll
      for (int n = 0; n < 4; ++n) {
        int row = wn * 64 + n * 16 + lrow;
        bf[n] = *reinterpret_cast<const f16x8*>(&Bs[row * 64 + ((cs ^ (row & 7)) * 8)]);
      }
#pragma unroll
      for (int m = 0; m < 4; ++m)
#pragma unroll
        for (int n = 0; n < 4; ++n)
          acc[m][n] = __builtin_amdgcn_mfma_f32_16x16x32_f16(af[m], bf[n], acc[m][n], 0, 0, 0);
    }
    __syncthreads();
  }
  // epilogue: ATOMIC accumulate — same token appears in two experts' lists and those
  // blocks run concurrently. Two commutative fp32 addends on zeroed buffer = deterministic.
#pragma unroll
  for (int m = 0; m < 4; ++m)
#pragma unroll
    for (int r = 0; r < 4; ++r) {
      int ri = r0 + wm * 64 + m * 16 + lk * 4 + r;
      if (ri < cnt) {
        int tok = lst[ri];
        float wg = wgt[ri];
        float* orow = out + (size_t)tok * H_DIM + c0 + wn * 64 + lrow;
#pragma unroll
        for (int n = 0; n < 4; ++n) atomicAdd(&orow[n * 16], wg * acc[m][n][r]);
      }
    }
}

// ---------------------------------------------------------------- host
extern "C" void kernel_launch(void* const* d_in, const int* in_sizes, int n_in,
                              void* d_out, int out_size, void* d_ws, size_t ws_size,
                              hipStream_t stream) {
  const float* x = (const float*)d_in[0];
  const float* gw = (const float*)d_in[1];
  const float* w1s = (const float*)d_in[2];
  const float* w2s = (const float*)d_in[3];
  const float* w3s = (const float*)d_in[4];
  float* out = (float*)d_out;

  char* ws = (char*)d_ws;
  f16* xh = (f16*)ws;                                   // 8 MiB
  f16* inter = (f16*)(ws + ((size_t)8 << 20));          // 72 MiB
  f16* w1t = (f16*)(ws + ((size_t)80 << 20));           // 64 MiB
  f16* w3t = (f16*)(ws + ((size_t)144 << 20));          // 64 MiB
  f16* w2t = (f16*)(ws + ((size_t)208 << 20));          // 64 MiB
  char* meta = ws + ((size_t)272 << 20);
  int* counts = (int*)meta;
  int* bases = (int*)(meta + 512);
  int* lists = (int*)(meta + 1024);
  float* wgts = (float*)(meta + 1024 + (size_t)NE * T_TOK * 4);

  hipMemsetAsync(out, 0, (size_t)out_size * sizeof(float), stream);
  hipMemsetAsync(meta, 0, 1024 + (size_t)NE * T_TOK * 8, stream);

  cast_x_kernel<<<dim3((T_TOK * H_DIM) / (4 * 256)), dim3(256), 0, stream>>>(x, xh);
  router_kernel<<<dim3(T_TOK), dim3(64), 0, stream>>>(x, gw, counts, lists, wgts);
  prefix_kernel<<<dim3(1), dim3(64), 0, stream>>>(counts, bases);
  // w1s/w3s: [H=1024][I=4096] -> [I][H];  w2s: [I=4096][H=1024] -> [H][I]
  transpose_cast_kernel<<<dim3(I_DIM / 64, H_DIM / 64, NE), dim3(256), 0, stream>>>(
      w1s, w1t, H_DIM, I_DIM);
  transpose_cast_kernel<<<dim3(I_DIM / 64, H_DIM / 64, NE), dim3(256), 0, stream>>>(
      w3s, w3t, H_DIM, I_DIM);
  transpose_cast_kernel<<<dim3(H_DIM / 64, I_DIM / 64, NE), dim3(256), 0, stream>>>(
      w2s, w2t, I_DIM, H_DIM);
  gemm_a_kernel<<<dim3(I_DIM / 128, T_TOK / 128, NE), dim3(256), 0, stream>>>(
      xh, w1t, w3t, counts, bases, lists, inter);
  gemm_b_kernel<<<dim3(H_DIM / 128, T_TOK / 128, NE), dim3(256), 0, stream>>>(
      inter, w2t, counts, bases, lists, wgts, out);
}